// Round 9
// baseline (211.321 us; speedup 1.0000x reference)
//
#include <hip/hip_runtime.h>

#define NBINS 4352                  // bin = float_bits(d)>>18 ; d<=~4 -> bin<=4128
#define ACC_OFF (3 * NBINS)         // ws_f word offset: per-layer n^2 sums [3]
#define DONE_OFF (ACC_OFF + 4)      // ws_u word offset: last-block ticket
#define NBLOCKS 1792

typedef float    f4v __attribute__((ext_vector_type(4)));
typedef _Float16 h4v __attribute__((ext_vector_type(4)));

__device__ __forceinline__ float bin_lo(int b)  { return __uint_as_float((unsigned)b << 18); }
__device__ __forceinline__ float bin_mid(int b) { return 0.5f * (bin_lo(b) + bin_lo(b + 1)); }

__device__ __forceinline__ unsigned agent_load_u(const unsigned* p) {
    return __hip_atomic_load(p, __ATOMIC_RELAXED, __HIP_MEMORY_SCOPE_AGENT);
}
__device__ __forceinline__ float agent_load_f(const float* p) {
    return __hip_atomic_load(p, __ATOMIC_RELAXED, __HIP_MEMORY_SCOPE_AGENT);
}

// Winner-block inline finalize: per layer, parallel chunk sums (counts *
// bin-midpoint), short serial top-down walk; boundary bin uses the uniform-
// within-bin model. All inputs were written with device-scope atomics; reads
// are agent-scope relaxed atomic loads (validated rounds 6/7, absmax 0.0).
__device__ void finalize_body(const unsigned* __restrict__ ws_u,
                              const float* __restrict__ ws_f,
                              float* __restrict__ out, unsigned* lds)
{
    unsigned* cchunk = lds;                  // [256]
    float*    schunk = (float*)(lds + 256);  // [256]
    const int tid = threadIdx.x;
    const int   targets[3] = {16778, 8389, 4195};   // cnt = N-1-floor(0.999(N-1))
    const float Ns[3]      = {16777216.f, 8388608.f, 4194304.f};
    const int   CHUNK = NBINS / 256;  // 17

    float total = 0.f;  // thread 0 only
    for (int layer = 0; layer < 3; ++layer) {
        const unsigned* gc = ws_u + layer * NBINS;
        unsigned c = 0; float sv = 0.f;
        const int b0 = tid * CHUNK;
        for (int i = 0; i < CHUNK; ++i) {
            unsigned cc = agent_load_u(gc + b0 + i);
            c += cc;
            if (cc) sv += (float)cc * bin_mid(b0 + i);
        }
        __syncthreads();   // prior-phase LDS reads done before overwrite
        cchunk[tid] = c; schunk[tid] = sv;
        __syncthreads();
        if (tid == 0) {
            const int target = targets[layer];
            long long cum = 0; float sAbove = 0.f;
            int ch = 255;
            while (ch >= 0 && cum + (long long)cchunk[ch] < target) {
                cum += cchunk[ch]; sAbove += schunk[ch]; --ch;
            }
            int bin = ch * CHUNK + CHUNK - 1;
            unsigned cb = agent_load_u(gc + bin);
            while (bin > ch * CHUNK && cum + (long long)cb < target) {
                cum += cb; sAbove += (float)cb * bin_mid(bin);
                --bin; cb = agent_load_u(gc + bin);
            }
            int j = target - (int)cum;           // elements taken from boundary bin
            float lo = bin_lo(bin), hi = bin_lo(bin + 1);
            float f  = (float)j / (float)cb;
            float topmean = hi - f * (hi - lo) * 0.5f;   // mean of top-j, uniform model
            topmean = fminf(fmaxf(topmean, lo), hi);
            float hard   = (sAbove + topmean * (float)j) / (float)target;
            float n2mean = agent_load_f(ws_f + ACC_OFF + layer) / Ns[layer];
            total += hard + n2mean;
        }
        __syncthreads();
    }
    if (tid == 0) out[0] = total;
}

// ---- round-4 body (measured best — DO NOT restructure the load loop; rounds
// 5/6 showed explicit pipelines collapse MLP / spill to scratch). Every block:
// 16K elements (P positions x C channels) of one image; every thread 16
// channels x 4 consecutive positions. t,s retained as f16 while f32 norms
// reduce through LDS; then register-only d histogram (no global re-read). ----
template<int C, int HWSHIFT, int PSHIFT, int LAYER>
__device__ __forceinline__ void hist_layer(
    const float* __restrict__ t, const float* __restrict__ s, const float* __restrict__ n,
    int lb, unsigned int* __restrict__ ws_u, float* __restrict__ ws_f,
    unsigned int* cnt_sh, float* inv_sh)
{
    const int HW  = 1 << HWSHIFT;
    const int P   = 1 << PSHIFT;        // positions per block: 256/128/64
    const int NPQ = P >> 2;             // position-quads per wave: 64/32/16
    const int G   = 1024 >> PSHIFT;     // norm partials per position: 4/8/16
    const int tid = threadIdx.x;
    const int w   = tid >> 6;
    const int l   = tid & 63;
    const int pq  = l & (NPQ - 1);      // which position-quad
    const int cs  = l >> (PSHIFT - 2);  // channel sub-group within wave

    const int p0 = lb << PSHIFT;        // first flat position (never straddles b)
    const int b  = p0 >> HWSHIFT;
    const int q  = p0 & (HW - 1);
    const int c0 = w * (C / 4) + cs * 16;
    const size_t base = ((size_t)(b * C + c0) << HWSHIFT) + q + 4 * pq;

    const float* tp = t + base;
    const float* sp = s + base;
    const float* np = n + base;

    // ---- pass 1: batched loads (12 float4 in flight), f32 norm accum, f16 retain ----
    h4v th[16], sh[16];
    f4v accT = {0.f,0.f,0.f,0.f}, accS = {0.f,0.f,0.f,0.f};
    float aN = 0.f;

    #pragma unroll
    for (int k0 = 0; k0 < 16; k0 += 4) {
        f4v tt[4], ss[4], nn[4];
        #pragma unroll
        for (int u = 0; u < 4; ++u) {
            const size_t o = (size_t)(k0 + u) << HWSHIFT;
            tt[u] = *(const f4v*)(tp + o);
            ss[u] = *(const f4v*)(sp + o);
            nn[u] = __builtin_nontemporal_load((const f4v*)(np + o));
        }
        #pragma unroll
        for (int u = 0; u < 4; ++u) {
            accT += tt[u] * tt[u];
            accS += ss[u] * ss[u];
            aN += nn[u].x*nn[u].x + nn[u].y*nn[u].y + nn[u].z*nn[u].z + nn[u].w*nn[u].w;
            th[k0+u] = (h4v){(_Float16)tt[u].x, (_Float16)tt[u].y,
                             (_Float16)tt[u].z, (_Float16)tt[u].w};
            sh[k0+u] = (h4v){(_Float16)ss[u].x, (_Float16)ss[u].y,
                             (_Float16)ss[u].z, (_Float16)ss[u].w};
        }
    }

    // cross-wave/lane-group norm combine via LDS overlay on cnt_sh
    float* ovT = (float*)cnt_sh;        // [G][P] = 1024 floats
    float* ovS = ovT + 1024;            // 1024 floats
    float* ovN = ovT + 2048;            // 4 floats
    const int g = (w * (64 / NPQ)) + cs;        // partial group id, 0..G-1
    ((f4v*)ovT)[g * NPQ + pq] = accT;           // linearizes to ovT[g*P + pos]
    ((f4v*)ovS)[g * NPQ + pq] = accS;
    #pragma unroll
    for (int o = 32; o > 0; o >>= 1) aN += __shfl_down(aN, o, 64);
    if (l == 0) ovN[w] = aN;
    __syncthreads();

    if (tid < P) {
        float nT = 0.f, nS = 0.f;
        #pragma unroll
        for (int gg = 0; gg < G; ++gg) { nT += ovT[gg * P + tid]; nS += ovS[gg * P + tid]; }
        inv_sh[tid]     = 1.0f / fmaxf(sqrtf(nT), 1e-12f);
        inv_sh[P + tid] = 1.0f / fmaxf(sqrtf(nS), 1e-12f);
    }
    if (tid == 0)
        atomicAdd(&ws_f[ACC_OFF + LAYER], ovN[0] + ovN[1] + ovN[2] + ovN[3]);
    __syncthreads();

    // ---- zero histogram ----
    for (int i = tid; i < NBINS / 4; i += 256)
        ((uint4*)cnt_sh)[i] = make_uint4(0u, 0u, 0u, 0u);
    __syncthreads();

    // ---- pass 2 (registers only): d = (t*invT - s*invS)^2, count histogram ----
    __builtin_amdgcn_s_setprio(1);      // r8: neutral-to-slightly-positive, keep
    f4v iT = ((const f4v*)inv_sh)[pq];
    f4v iS = ((const f4v*)(inv_sh + P))[pq];
    #pragma unroll
    for (int k = 0; k < 16; ++k) {
        f4v tv = {(float)th[k].x, (float)th[k].y, (float)th[k].z, (float)th[k].w};
        f4v sv = {(float)sh[k].x, (float)sh[k].y, (float)sh[k].z, (float)sh[k].w};
        f4v a  = tv * iT - sv * iS;
        f4v d  = a * a;
        unsigned b0 = min(__float_as_uint(d.x) >> 18, (unsigned)(NBINS - 1));
        unsigned b1 = min(__float_as_uint(d.y) >> 18, (unsigned)(NBINS - 1));
        unsigned b2 = min(__float_as_uint(d.z) >> 18, (unsigned)(NBINS - 1));
        unsigned b3 = min(__float_as_uint(d.w) >> 18, (unsigned)(NBINS - 1));
        atomicAdd(&cnt_sh[b0], 1u);
        atomicAdd(&cnt_sh[b1], 1u);
        atomicAdd(&cnt_sh[b2], 1u);
        atomicAdd(&cnt_sh[b3], 1u);
    }
    __syncthreads();

    // ---- flush nonzero bins to global per-layer histogram ----
    unsigned int* gc = ws_u + LAYER * NBINS;
    for (int i = tid; i < NBINS; i += 256) {
        unsigned c = cnt_sh[i];
        if (c) atomicAdd(&gc[i], c);
    }
    __builtin_amdgcn_s_setprio(0);
}

// Grid: 1792 uniform blocks = 256 (layer2) + 512 (layer1) + 1024 (layer0).
// Last-finishing block runs finalize inline. Ticket is RELAXED (round 7:
// acq_rel emitted per-block cache maintenance, +140 us). Ordering argument:
// all data writes are device-scope atomics; __syncthreads drains vmcnt(0)
// before the ticket, so data is at the coherence point before the increment.
__global__ __launch_bounds__(256, 6) void stfpm_main(
    const float* __restrict__ t0, const float* __restrict__ s0, const float* __restrict__ n0,
    const float* __restrict__ t1, const float* __restrict__ s1, const float* __restrict__ n1,
    const float* __restrict__ t2, const float* __restrict__ s2, const float* __restrict__ n2,
    unsigned int* __restrict__ ws_u, float* __restrict__ ws_f, float* __restrict__ out)
{
    __shared__ __align__(16) unsigned int cnt_sh[NBINS];  // 17.4 KB
    __shared__ __align__(16) float inv_sh[512];
    __shared__ unsigned last_flag;

    const int bid = blockIdx.x;
    if (bid < 256)
        hist_layer<256, 10, 6, 2>(t2, s2, n2, bid,       ws_u, ws_f, cnt_sh, inv_sh);
    else if (bid < 768)
        hist_layer<128, 12, 7, 1>(t1, s1, n1, bid - 256, ws_u, ws_f, cnt_sh, inv_sh);
    else
        hist_layer<64,  14, 8, 0>(t0, s0, n0, bid - 768, ws_u, ws_f, cnt_sh, inv_sh);

    __syncthreads();   // drain this block's global atomics (vmcnt 0)
    if (threadIdx.x == 0)
        last_flag = (__hip_atomic_fetch_add(&ws_u[DONE_OFF], 1u,
                         __ATOMIC_RELAXED, __HIP_MEMORY_SCOPE_AGENT)
                     == (unsigned)(NBLOCKS - 1));
    __syncthreads();
    if (last_flag)
        finalize_body(ws_u, ws_f, out, cnt_sh);
}

extern "C" void kernel_launch(void* const* d_in, const int* in_sizes, int n_in,
                              void* d_out, int out_size, void* d_ws, size_t ws_size,
                              hipStream_t stream)
{
    const float* t0 = (const float*)d_in[0];
    const float* s0 = (const float*)d_in[1];
    const float* n0 = (const float*)d_in[2];
    const float* t1 = (const float*)d_in[3];
    const float* s1 = (const float*)d_in[4];
    const float* n1 = (const float*)d_in[5];
    const float* t2 = (const float*)d_in[6];
    const float* s2 = (const float*)d_in[7];
    const float* n2 = (const float*)d_in[8];

    // zero per-layer histograms + n^2 accumulators + ticket (ws is NOT
    // re-poisoned between replays; memset is stream-ordered, graph-capturable)
    hipMemsetAsync(d_ws, 0, (size_t)(ACC_OFF + 8) * 4, stream);

    stfpm_main<<<NBLOCKS, 256, 0, stream>>>(t0, s0, n0, t1, s1, n1, t2, s2, n2,
                                            (unsigned int*)d_ws, (float*)d_ws,
                                            (float*)d_out);
}

// Round 10
// 162.140 us; speedup vs baseline: 1.3033x; 1.3033x over previous
//
#include <hip/hip_runtime.h>

#define NBINS 4352                 // bin = float_bits(d)>>18 ; d<=~4 -> bin<=4128
#define ACC_OFF (3 * NBINS)        // word offset of per-layer n^2 accumulators in ws

typedef float    f4v __attribute__((ext_vector_type(4)));
typedef _Float16 h4v __attribute__((ext_vector_type(4)));

// Uniform-cost fused body: every block processes 16K elements (P positions x C
// channels, P*C = 16384) of one batch image. Every thread owns exactly 16
// channels x 4 consecutive positions (one float4 per channel). Single pass:
// t,s retained in registers as f16 while f32 norms are reduced, then d is
// histogrammed from registers (no global re-read).
//
// Hard-won constraints (do not violate):
//  - DO NOT restructure the load loop (r5/r6: explicit pipelines collapsed MLP
//    or spilled to scratch).
//  - DO NOT fuse finalize behind a fenced ticket (r7: acq_rel ticket = +140us
//    cache-maintenance stalls; r9 relaxed-ticket run polluted by VGPR collapse).
//  - launch_bounds waves arg is a HARD VGPR CAP of floor(512/w): body needs 84
//    VGPRs, so w<=5 ((256,6) -> cap ~80 -> VGPR fell to 40, FETCH 172->316MB,
//    2.2x slower, r9). (256,5): cap 102 >= 84.
template<int C, int HWSHIFT, int PSHIFT, int LAYER>
__device__ __forceinline__ void hist_layer(
    const float* __restrict__ t, const float* __restrict__ s, const float* __restrict__ n,
    int lb, unsigned int* __restrict__ ws_u, float* __restrict__ ws_f,
    unsigned int* cnt_sh, float* inv_sh)
{
    const int HW  = 1 << HWSHIFT;
    const int P   = 1 << PSHIFT;        // positions per block: 256/128/64
    const int NPQ = P >> 2;             // position-quads per wave: 64/32/16
    const int G   = 1024 >> PSHIFT;     // norm partials per position: 4/8/16
    const int tid = threadIdx.x;
    const int w   = tid >> 6;
    const int l   = tid & 63;
    const int pq  = l & (NPQ - 1);      // which position-quad
    const int cs  = l >> (PSHIFT - 2);  // channel sub-group within wave

    const int p0 = lb << PSHIFT;        // first flat position (never straddles b)
    const int b  = p0 >> HWSHIFT;
    const int q  = p0 & (HW - 1);
    const int c0 = w * (C / 4) + cs * 16;
    const size_t base = ((size_t)(b * C + c0) << HWSHIFT) + q + 4 * pq;

    const float* tp = t + base;
    const float* sp = s + base;
    const float* np = n + base;

    // ---- pass 1: batched loads (12 float4 in flight), f32 norm accum, f16 retain ----
    h4v th[16], sh[16];
    f4v accT = {0.f,0.f,0.f,0.f}, accS = {0.f,0.f,0.f,0.f};
    float aN = 0.f;

    #pragma unroll
    for (int k0 = 0; k0 < 16; k0 += 4) {
        f4v tt[4], ss[4], nn[4];
        #pragma unroll
        for (int u = 0; u < 4; ++u) {
            const size_t o = (size_t)(k0 + u) << HWSHIFT;
            tt[u] = *(const f4v*)(tp + o);
            ss[u] = *(const f4v*)(sp + o);
            nn[u] = __builtin_nontemporal_load((const f4v*)(np + o));
        }
        #pragma unroll
        for (int u = 0; u < 4; ++u) {
            accT += tt[u] * tt[u];
            accS += ss[u] * ss[u];
            aN += nn[u].x*nn[u].x + nn[u].y*nn[u].y + nn[u].z*nn[u].z + nn[u].w*nn[u].w;
            th[k0+u] = (h4v){(_Float16)tt[u].x, (_Float16)tt[u].y,
                             (_Float16)tt[u].z, (_Float16)tt[u].w};
            sh[k0+u] = (h4v){(_Float16)ss[u].x, (_Float16)ss[u].y,
                             (_Float16)ss[u].z, (_Float16)ss[u].w};
        }
    }

    // cross-wave/lane-group norm combine via LDS overlay on cnt_sh
    float* ovT = (float*)cnt_sh;        // [G][P] = 1024 floats
    float* ovS = ovT + 1024;            // 1024 floats
    float* ovN = ovT + 2048;            // 4 floats
    const int g = (w * (64 / NPQ)) + cs;        // partial group id, 0..G-1
    ((f4v*)ovT)[g * NPQ + pq] = accT;           // linearizes to ovT[g*P + pos]
    ((f4v*)ovS)[g * NPQ + pq] = accS;
    #pragma unroll
    for (int o = 32; o > 0; o >>= 1) aN += __shfl_down(aN, o, 64);
    if (l == 0) ovN[w] = aN;
    __syncthreads();

    if (tid < P) {
        float nT = 0.f, nS = 0.f;
        #pragma unroll
        for (int gg = 0; gg < G; ++gg) { nT += ovT[gg * P + tid]; nS += ovS[gg * P + tid]; }
        inv_sh[tid]     = 1.0f / fmaxf(sqrtf(nT), 1e-12f);
        inv_sh[P + tid] = 1.0f / fmaxf(sqrtf(nS), 1e-12f);
    }
    if (tid == 0)
        atomicAdd(&ws_f[ACC_OFF + LAYER], ovN[0] + ovN[1] + ovN[2] + ovN[3]);
    __syncthreads();

    // ---- zero histogram ----
    for (int i = tid; i < NBINS / 4; i += 256)
        ((uint4*)cnt_sh)[i] = make_uint4(0u, 0u, 0u, 0u);
    __syncthreads();

    // ---- pass 2 (registers only): d = (t*invT - s*invS)^2, count histogram ----
    __builtin_amdgcn_s_setprio(1);      // r8: neutral-to-slightly-positive, keep
    f4v iT = ((const f4v*)inv_sh)[pq];
    f4v iS = ((const f4v*)(inv_sh + P))[pq];
    #pragma unroll
    for (int k = 0; k < 16; ++k) {
        f4v tv = {(float)th[k].x, (float)th[k].y, (float)th[k].z, (float)th[k].w};
        f4v sv = {(float)sh[k].x, (float)sh[k].y, (float)sh[k].z, (float)sh[k].w};
        f4v a  = tv * iT - sv * iS;
        f4v d  = a * a;
        unsigned b0 = min(__float_as_uint(d.x) >> 18, (unsigned)(NBINS - 1));
        unsigned b1 = min(__float_as_uint(d.y) >> 18, (unsigned)(NBINS - 1));
        unsigned b2 = min(__float_as_uint(d.z) >> 18, (unsigned)(NBINS - 1));
        unsigned b3 = min(__float_as_uint(d.w) >> 18, (unsigned)(NBINS - 1));
        atomicAdd(&cnt_sh[b0], 1u);
        atomicAdd(&cnt_sh[b1], 1u);
        atomicAdd(&cnt_sh[b2], 1u);
        atomicAdd(&cnt_sh[b3], 1u);
    }
    __syncthreads();

    // ---- flush nonzero bins to global per-layer histogram ----
    unsigned int* gc = ws_u + LAYER * NBINS;
    for (int i = tid; i < NBINS; i += 256) {
        unsigned c = cnt_sh[i];
        if (c) atomicAdd(&gc[i], c);
    }
    __builtin_amdgcn_s_setprio(0);
}

// Grid: 256 (layer2) + 512 (layer1) + 1024 (layer0) = 1792 = 7 * 256 uniform blocks.
__global__ __launch_bounds__(256, 5) void stfpm_hist(
    const float* __restrict__ t0, const float* __restrict__ s0, const float* __restrict__ n0,
    const float* __restrict__ t1, const float* __restrict__ s1, const float* __restrict__ n1,
    const float* __restrict__ t2, const float* __restrict__ s2, const float* __restrict__ n2,
    unsigned int* __restrict__ ws_u, float* __restrict__ ws_f)
{
    __shared__ __align__(16) unsigned int cnt_sh[NBINS];  // 17.4 KB
    __shared__ __align__(16) float inv_sh[512];
    const int bid = blockIdx.x;
    if (bid < 256)
        hist_layer<256, 10, 6, 2>(t2, s2, n2, bid,       ws_u, ws_f, cnt_sh, inv_sh);
    else if (bid < 768)
        hist_layer<128, 12, 7, 1>(t1, s1, n1, bid - 256, ws_u, ws_f, cnt_sh, inv_sh);
    else
        hist_layer<64,  14, 8, 0>(t0, s0, n0, bid - 768, ws_u, ws_f, cnt_sh, inv_sh);
}

__device__ __forceinline__ float bin_mid(int b) {
    float lo = __uint_as_float((unsigned)b << 18);
    float hi = __uint_as_float((unsigned)(b + 1) << 18);
    return 0.5f * (lo + hi);
}

// Single block: per layer, scan counts from the top; full bins above the
// boundary contribute cnt * bin-midpoint; boundary bin uses the uniform-
// within-bin model for its top-j elements. Adds mean(n^2); writes the scalar.
__global__ __launch_bounds__(256) void stfpm_finalize(
    const unsigned int* __restrict__ ws_u, const float* __restrict__ ws_f,
    float* __restrict__ out)
{
    __shared__ unsigned int cchunk[256];
    __shared__ float        schunk[256];
    const int tid = threadIdx.x;

    const int   targets[3] = {16778, 8389, 4195};  // cnt = N-1-floor(0.999(N-1))
    const float Ns[3]      = {16777216.f, 8388608.f, 4194304.f};
    const int   CHUNK = NBINS / 256;  // 17

    float total = 0.f;  // thread 0 only
    for (int layer = 0; layer < 3; ++layer) {
        const unsigned int* gc = ws_u + layer * NBINS;
        unsigned int c = 0; float sv = 0.f;
        const int b0 = tid * CHUNK;
        for (int i = 0; i < CHUNK; ++i) {
            unsigned cc = gc[b0 + i];
            c += cc;
            if (cc) sv += (float)cc * bin_mid(b0 + i);
        }
        __syncthreads();
        cchunk[tid] = c; schunk[tid] = sv;
        __syncthreads();
        if (tid == 0) {
            const int target = targets[layer];
            long long cum = 0; float sAbove = 0.f;
            int ch = 255;
            while (ch >= 0 && cum + (long long)cchunk[ch] < target) {
                cum += cchunk[ch]; sAbove += schunk[ch]; --ch;
            }
            int bin = ch * CHUNK + CHUNK - 1;
            while (bin >= ch * CHUNK && cum + (long long)gc[bin] < target) {
                unsigned cc = gc[bin];
                cum += cc; sAbove += (float)cc * bin_mid(bin); --bin;
            }
            unsigned cb = gc[bin];          // boundary bin count (>=1)
            int j = target - (int)cum;      // elements taken from boundary bin
            float lo = __uint_as_float((unsigned)bin << 18);
            float hi = __uint_as_float((unsigned)(bin + 1) << 18);
            float wd = hi - lo;
            float f  = (float)j / (float)cb;
            float topmean = hi - f * wd * 0.5f;  // mean of top-j under uniform model
            topmean = fminf(fmaxf(topmean, lo), hi);
            float hard   = (sAbove + topmean * (float)j) / (float)target;
            float n2mean = ws_f[ACC_OFF + layer] / Ns[layer];
            total += hard + n2mean;
        }
        __syncthreads();
    }
    if (tid == 0) out[0] = total;
}

extern "C" void kernel_launch(void* const* d_in, const int* in_sizes, int n_in,
                              void* d_out, int out_size, void* d_ws, size_t ws_size,
                              hipStream_t stream)
{
    const float* t0 = (const float*)d_in[0];
    const float* s0 = (const float*)d_in[1];
    const float* n0 = (const float*)d_in[2];
    const float* t1 = (const float*)d_in[3];
    const float* s1 = (const float*)d_in[4];
    const float* n1 = (const float*)d_in[5];
    const float* t2 = (const float*)d_in[6];
    const float* s2 = (const float*)d_in[7];
    const float* n2 = (const float*)d_in[8];

    // zero per-layer histograms + accumulators (ws is NOT re-poisoned between replays)
    hipMemsetAsync(d_ws, 0, (size_t)(ACC_OFF + 8) * 4, stream);

    stfpm_hist<<<1792, 256, 0, stream>>>(t0, s0, n0, t1, s1, n1, t2, s2, n2,
                                         (unsigned int*)d_ws, (float*)d_ws);
    stfpm_finalize<<<1, 256, 0, stream>>>((const unsigned int*)d_ws,
                                          (const float*)d_ws, (float*)d_out);
}

// Round 11
// 81.305 us; speedup vs baseline: 2.5991x; 1.9942x over previous
//
#include <hip/hip_runtime.h>

#define NBINS 2304                 // rebased: bin = (float_bits(d)>>18) - BINBASE
#define BINBASE 2048               // bin 0 <-> d ~ 5.4e-19; d<=4 -> bin <= 2113
#define ACC_OFF (3 * NBINS)        // word offset of per-layer n^2 accumulators in ws

typedef float    f4v __attribute__((ext_vector_type(4)));
typedef _Float16 h4v __attribute__((ext_vector_type(4)));

// Uniform-cost fused body: every block processes 16K elements (P positions x C
// channels, P*C = 16384) of one batch image. Every thread owns exactly 16
// channels x 4 consecutive positions (one float4 per channel). Single pass:
// t,s retained in registers as f16 while f32 norms are reduced, then d is
// histogrammed from registers (no global re-read).
//
// Hard-won constraints (do not violate):
//  - DO NOT restructure the load loop (r5/r6: explicit pipelines collapsed MLP
//    or spilled to scratch).
//  - DO NOT fuse finalize behind a ticket (r7: acq_rel = +140us cache-maint
//    stalls; r9/r10 relaxed tests polluted by VGPR collapse).
//  - launch_bounds waves-arg >= 4 flips the compiler into pressure-limited
//    scheduling and spills th/sh (r3/r5/r9/r10: VGPR 36/52/40/48, scratch
//    WRITE visible, 1.5-2.9x slower). KEEP (256,3); VGPR must report 84.
template<int C, int HWSHIFT, int PSHIFT, int LAYER>
__device__ __forceinline__ void hist_layer(
    const float* __restrict__ t, const float* __restrict__ s, const float* __restrict__ n,
    int lb, unsigned int* __restrict__ ws_u, float* __restrict__ ws_f,
    unsigned int* cnt_sh, float* ov_sh, float* inv_sh)
{
    const int HW  = 1 << HWSHIFT;
    const int P   = 1 << PSHIFT;        // positions per block: 256/128/64
    const int NPQ = P >> 2;             // position-quads per wave: 64/32/16
    const int G   = 1024 >> PSHIFT;     // norm partials per position: 4/8/16
    const int tid = threadIdx.x;
    const int w   = tid >> 6;
    const int l   = tid & 63;
    const int pq  = l & (NPQ - 1);      // which position-quad
    const int cs  = l >> (PSHIFT - 2);  // channel sub-group within wave

    const int p0 = lb << PSHIFT;        // first flat position (never straddles b)
    const int b  = p0 >> HWSHIFT;
    const int q  = p0 & (HW - 1);
    const int c0 = w * (C / 4) + cs * 16;
    const size_t base = ((size_t)(b * C + c0) << HWSHIFT) + q + 4 * pq;

    const float* tp = t + base;
    const float* sp = s + base;
    const float* np = n + base;

    // ---- zero histogram up-front: hides under the in-flight global loads;
    //      completion is covered by the first __syncthreads below ----
    #pragma unroll
    for (int i = tid; i < NBINS / 4; i += 256)
        ((uint4*)cnt_sh)[i] = make_uint4(0u, 0u, 0u, 0u);

    // ---- pass 1: batched loads (12 float4 in flight), f32 norm accum, f16 retain ----
    h4v th[16], sh[16];
    f4v accT = {0.f,0.f,0.f,0.f}, accS = {0.f,0.f,0.f,0.f};
    float aN = 0.f;

    #pragma unroll
    for (int k0 = 0; k0 < 16; k0 += 4) {
        f4v tt[4], ss[4], nn[4];
        #pragma unroll
        for (int u = 0; u < 4; ++u) {
            const size_t o = (size_t)(k0 + u) << HWSHIFT;
            tt[u] = *(const f4v*)(tp + o);
            ss[u] = *(const f4v*)(sp + o);
            nn[u] = __builtin_nontemporal_load((const f4v*)(np + o));
        }
        #pragma unroll
        for (int u = 0; u < 4; ++u) {
            accT += tt[u] * tt[u];
            accS += ss[u] * ss[u];
            aN += nn[u].x*nn[u].x + nn[u].y*nn[u].y + nn[u].z*nn[u].z + nn[u].w*nn[u].w;
            th[k0+u] = (h4v){(_Float16)tt[u].x, (_Float16)tt[u].y,
                             (_Float16)tt[u].z, (_Float16)tt[u].w};
            sh[k0+u] = (h4v){(_Float16)ss[u].x, (_Float16)ss[u].y,
                             (_Float16)ss[u].z, (_Float16)ss[u].w};
        }
    }

    // cross-wave/lane-group norm combine via dedicated ov_sh buffer
    float* ovT = ov_sh;                 // [G][P] = 1024 floats
    float* ovS = ov_sh + 1024;          // 1024 floats
    float* ovN = ov_sh + 2048;          // 4 floats
    const int g = (w * (64 / NPQ)) + cs;        // partial group id, 0..G-1
    ((f4v*)ovT)[g * NPQ + pq] = accT;           // linearizes to ovT[g*P + pos]
    ((f4v*)ovS)[g * NPQ + pq] = accS;
    #pragma unroll
    for (int o = 32; o > 0; o >>= 1) aN += __shfl_down(aN, o, 64);
    if (l == 0) ovN[w] = aN;
    __syncthreads();

    if (tid < P) {
        float nT = 0.f, nS = 0.f;
        #pragma unroll
        for (int gg = 0; gg < G; ++gg) { nT += ovT[gg * P + tid]; nS += ovS[gg * P + tid]; }
        inv_sh[tid]     = 1.0f / fmaxf(sqrtf(nT), 1e-12f);
        inv_sh[P + tid] = 1.0f / fmaxf(sqrtf(nS), 1e-12f);
    }
    if (tid == 0)
        atomicAdd(&ws_f[ACC_OFF + LAYER], ovN[0] + ovN[1] + ovN[2] + ovN[3]);
    __syncthreads();

    // ---- pass 2 (registers only): d = (t*invT - s*invS)^2, count histogram ----
    __builtin_amdgcn_s_setprio(1);      // r8: neutral-to-slightly-positive, keep
    f4v iT = ((const f4v*)inv_sh)[pq];
    f4v iS = ((const f4v*)(inv_sh + P))[pq];
    #pragma unroll
    for (int k = 0; k < 16; ++k) {
        f4v tv = {(float)th[k].x, (float)th[k].y, (float)th[k].z, (float)th[k].w};
        f4v sv = {(float)sh[k].x, (float)sh[k].y, (float)sh[k].z, (float)sh[k].w};
        f4v a  = tv * iT - sv * iS;
        f4v d  = a * a;
        int b0 = min(max((int)(__float_as_uint(d.x) >> 18) - BINBASE, 0), NBINS - 1);
        int b1 = min(max((int)(__float_as_uint(d.y) >> 18) - BINBASE, 0), NBINS - 1);
        int b2 = min(max((int)(__float_as_uint(d.z) >> 18) - BINBASE, 0), NBINS - 1);
        int b3 = min(max((int)(__float_as_uint(d.w) >> 18) - BINBASE, 0), NBINS - 1);
        atomicAdd(&cnt_sh[b0], 1u);
        atomicAdd(&cnt_sh[b1], 1u);
        atomicAdd(&cnt_sh[b2], 1u);
        atomicAdd(&cnt_sh[b3], 1u);
    }
    __syncthreads();

    // ---- flush nonzero bins to global per-layer histogram ----
    unsigned int* gc = ws_u + LAYER * NBINS;
    #pragma unroll
    for (int i = tid; i < NBINS; i += 256) {
        unsigned c = cnt_sh[i];
        if (c) atomicAdd(&gc[i], c);
    }
    __builtin_amdgcn_s_setprio(0);
}

// Grid: 256 (layer2) + 512 (layer1) + 1024 (layer0) = 1792 = 7 * 256 uniform blocks.
__global__ __launch_bounds__(256, 3) void stfpm_hist(
    const float* __restrict__ t0, const float* __restrict__ s0, const float* __restrict__ n0,
    const float* __restrict__ t1, const float* __restrict__ s1, const float* __restrict__ n1,
    const float* __restrict__ t2, const float* __restrict__ s2, const float* __restrict__ n2,
    unsigned int* __restrict__ ws_u, float* __restrict__ ws_f)
{
    __shared__ __align__(16) unsigned int cnt_sh[NBINS];  // 9.2 KB
    __shared__ __align__(16) float ov_sh[2052];           // 8.2 KB norm overlay
    __shared__ __align__(16) float inv_sh[512];           // 2 KB
    const int bid = blockIdx.x;
    if (bid < 256)
        hist_layer<256, 10, 6, 2>(t2, s2, n2, bid,       ws_u, ws_f, cnt_sh, ov_sh, inv_sh);
    else if (bid < 768)
        hist_layer<128, 12, 7, 1>(t1, s1, n1, bid - 256, ws_u, ws_f, cnt_sh, ov_sh, inv_sh);
    else
        hist_layer<64,  14, 8, 0>(t0, s0, n0, bid - 768, ws_u, ws_f, cnt_sh, ov_sh, inv_sh);
}

__device__ __forceinline__ float bin_lo(int b) {
    return __uint_as_float((unsigned)(b + BINBASE) << 18);
}
__device__ __forceinline__ float bin_mid(int b) {
    return 0.5f * (bin_lo(b) + bin_lo(b + 1));
}

// Single block: per layer, scan counts from the top; full bins above the
// boundary contribute cnt * bin-midpoint; boundary bin uses the uniform-
// within-bin model for its top-j elements. Adds mean(n^2); writes the scalar.
__global__ __launch_bounds__(256) void stfpm_finalize(
    const unsigned int* __restrict__ ws_u, const float* __restrict__ ws_f,
    float* __restrict__ out)
{
    __shared__ unsigned int cchunk[256];
    __shared__ float        schunk[256];
    const int tid = threadIdx.x;

    const int   targets[3] = {16778, 8389, 4195};  // cnt = N-1-floor(0.999(N-1))
    const float Ns[3]      = {16777216.f, 8388608.f, 4194304.f};
    const int   CHUNK = NBINS / 256;  // 9

    float total = 0.f;  // thread 0 only
    for (int layer = 0; layer < 3; ++layer) {
        const unsigned int* gc = ws_u + layer * NBINS;
        unsigned int c = 0; float sv = 0.f;
        const int b0 = tid * CHUNK;
        for (int i = 0; i < CHUNK; ++i) {
            unsigned cc = gc[b0 + i];
            c += cc;
            if (cc) sv += (float)cc * bin_mid(b0 + i);
        }
        __syncthreads();
        cchunk[tid] = c; schunk[tid] = sv;
        __syncthreads();
        if (tid == 0) {
            const int target = targets[layer];
            long long cum = 0; float sAbove = 0.f;
            int ch = 255;
            while (ch >= 0 && cum + (long long)cchunk[ch] < target) {
                cum += cchunk[ch]; sAbove += schunk[ch]; --ch;
            }
            int bin = ch * CHUNK + CHUNK - 1;
            while (bin >= ch * CHUNK && cum + (long long)gc[bin] < target) {
                unsigned cc = gc[bin];
                cum += cc; sAbove += (float)cc * bin_mid(bin); --bin;
            }
            unsigned cb = gc[bin];          // boundary bin count (>=1)
            int j = target - (int)cum;      // elements taken from boundary bin
            float lo = bin_lo(bin), hi = bin_lo(bin + 1);
            float wd = hi - lo;
            float f  = (float)j / (float)cb;
            float topmean = hi - f * wd * 0.5f;  // mean of top-j under uniform model
            topmean = fminf(fmaxf(topmean, lo), hi);
            float hard   = (sAbove + topmean * (float)j) / (float)target;
            float n2mean = ws_f[ACC_OFF + layer] / Ns[layer];
            total += hard + n2mean;
        }
        __syncthreads();
    }
    if (tid == 0) out[0] = total;
}

extern "C" void kernel_launch(void* const* d_in, const int* in_sizes, int n_in,
                              void* d_out, int out_size, void* d_ws, size_t ws_size,
                              hipStream_t stream)
{
    const float* t0 = (const float*)d_in[0];
    const float* s0 = (const float*)d_in[1];
    const float* n0 = (const float*)d_in[2];
    const float* t1 = (const float*)d_in[3];
    const float* s1 = (const float*)d_in[4];
    const float* n1 = (const float*)d_in[5];
    const float* t2 = (const float*)d_in[6];
    const float* s2 = (const float*)d_in[7];
    const float* n2 = (const float*)d_in[8];

    // zero per-layer histograms + accumulators (ws is NOT re-poisoned between replays)
    hipMemsetAsync(d_ws, 0, (size_t)(ACC_OFF + 8) * 4, stream);

    stfpm_hist<<<1792, 256, 0, stream>>>(t0, s0, n0, t1, s1, n1, t2, s2, n2,
                                         (unsigned int*)d_ws, (float*)d_ws);
    stfpm_finalize<<<1, 256, 0, stream>>>((const unsigned int*)d_ws,
                                          (const float*)d_ws, (float*)d_out);
}